// Round 5
// baseline (33553.745 us; speedup 1.0000x reference)
//
#include <hip/hip_runtime.h>
#include <hip/hip_bf16.h>
#include <stdint.h>

#define S_LEN 8192
#define CH_L 16
#define CDIM 64
#define WDIM 256
#define CHID 128
#define WHID 512
#define NTAG 64
#define GWORD 32

typedef __hip_bfloat16 bf16;
typedef long long i64;

__device__ __forceinline__ float bflo(uint32_t w){ union{uint32_t u;float f;}v; v.u=w<<16; return v.f; }
__device__ __forceinline__ float bfhi(uint32_t w){ union{uint32_t u;float f;}v; v.u=w&0xffff0000u; return v.f; }
__device__ __forceinline__ float bf2f(uint16_t h){ union{uint32_t u;float f;}v; v.u=((uint32_t)h)<<16; return v.f; }
__device__ __forceinline__ uint16_t f2bb(float f){ bf16 h=__float2bfloat16(f); union{uint16_t u;bf16 b;}v; v.b=h; return v.u; }
__device__ __forceinline__ float sigf(float x){ return 1.0f/(1.0f+__expf(-x)); }
__device__ __forceinline__ float tanhfast(float x){ x=fminf(fmaxf(x,-15.f),15.f); float e=__expf(2.f*x); return (e-1.f)/(e+1.f); }

// dtype-agnostic element access (isbf: 1 = bf16 array, 0 = fp32 array)
__device__ __forceinline__ float getf(const void* p, i64 i, int isbf){
    return isbf ? bf2f(((const uint16_t*)p)[i]) : ((const float*)p)[i];
}
// elements 2j, 2j+1 packed as a bf16-pair dword
__device__ __forceinline__ uint32_t getpair(const void* p, i64 j, int isbf){
    if (isbf) return ((const uint32_t*)p)[j];
    float a=((const float*)p)[2*j], b=((const float*)p)[2*j+1];
    return (uint32_t)f2bb(a) | ((uint32_t)f2bb(b)<<16);
}

// ---------------------------------------------------------------------------
// Sniff: bf16 vs fp32 for the float inputs (expected: fp32 -> flag=0).
// ---------------------------------------------------------------------------
__global__ void sniff_kernel(const uint32_t* __restrict__ wWhh_raw, int* __restrict__ flag){
    int lane = threadIdx.x;
    uint32_t w = wWhh_raw[lane];
    uint16_t h = (uint16_t)(w & 0xFFFFu);
    uint32_t e = (h>>7)&0xFF;
    int ok = (h==0) || (e>=0x58 && e<=0x7E);
    unsigned long long m = __ballot(ok);
    if (lane==0) *flag = (__popcll(m) >= 32) ? 1 : 0;
}

// ---------------------------------------------------------------------------
// Canonicalize (small): E table, cWhh transpose, summed biases, cnt, ring 0.
// ---------------------------------------------------------------------------
__global__ void canon_kernel(const int* __restrict__ flag,
    const void* cemb, const void* cWih, const void* cWhh,
    const void* cbih, const void* cbhh, const void* wbih, const void* wbhh,
    const void* clsb,
    float* __restrict__ E, uint32_t* __restrict__ whhT_c, float* __restrict__ wb,
    float* __restrict__ clsb_f, int* __restrict__ cnt, uint32_t* __restrict__ hring)
{
    int isbf = *flag;
    int blk = blockIdx.x, tid = threadIdx.x;
    if (blk < 128) {                       // E[ch][512] = cemb[ch] @ cWih^T + biases
        int ch = blk;
        for (int rr=0; rr<2; rr++){
            int r = tid + rr*256;
            float acc = getf(cbih,r,isbf) + getf(cbhh,r,isbf);
            for (int k=0;k<64;k++)
                acc += getf(cemb,(i64)ch*64+k,isbf)*getf(cWih,(i64)r*64+k,isbf);
            E[ch*512+r] = acc;
        }
    } else if (blk < 132) {                // cWhh [512][128] -> [kp 64][row 512] pairs
        int base = (blk-128)*8192;
        for (int i=0;i<32;i++){
            int j = base + tid + i*256;
            int kp=j>>9, row=j&511;
            whhT_c[j] = getpair(cWhh,(i64)row*64+kp,isbf);
        }
    } else {                               // wb, clsb_f, cnt, ring slot 0
        for (int j=tid;j<2048;j+=256) wb[j] = getf(wbih,j,isbf)+getf(wbhh,j,isbf);
        for (int j=tid;j<64;j+=256)   clsb_f[j] = getf(clsb,j,isbf);
        for (int j=tid;j<S_LEN;j+=256) cnt[j]=0;
        for (int j=tid;j<256;j+=256)  hring[j]=0u;
    }
}

// ---------------------------------------------------------------------------
// Char LSTM: 8 words/block, 512 threads. Wave wq owns word wq; lane l owns
// units l and l+64 with all four gates -> c/h update fully thread-local.
// ---------------------------------------------------------------------------
__launch_bounds__(512)
__global__ void char_lstm_kernel(const int* __restrict__ chars, const int* __restrict__ lens,
                                 const float* __restrict__ E, const uint32_t* __restrict__ whhT,
                                 bf16* __restrict__ feat)
{
    __shared__ float h_sm[8][CHID];
    __shared__ int   ch_sm[8][CH_L];
    __shared__ int   len_sm[8];
    int tid = threadIdx.x;
    int w0  = blockIdx.x*8;
    if (tid < 128){ int w=tid>>4, s=tid&15; ch_sm[w][s] = chars[(w0+w)*CH_L + s]; }
    if (tid < 8)  len_sm[tid] = lens[w0+tid];
    int wq = tid>>6, l = tid&63;
    h_sm[wq][l]=0.f; h_sm[wq][l+64]=0.f;
    float c0=0.f, c1=0.f, f0=0.f, f1=0.f;
    __syncthreads();
    for (int s=0; s<CH_L; s++){
        int ch = ch_sm[wq][s];
        const float* Erow = E + ch*512;
        float acc[8];
        #pragma unroll
        for (int r=0;r<8;r++) acc[r]=Erow[r*64+l];
        for (int kp=0; kp<64; kp++){
            float2 h2 = *(const float2*)&h_sm[wq][2*kp];
            const uint32_t* wp = whhT + kp*512 + l;
            #pragma unroll
            for (int r=0;r<8;r++){
                uint32_t wv = wp[r*64];
                acc[r] += h2.x*bflo(wv) + h2.y*bfhi(wv);
            }
        }
        float iA=sigf(acc[0]), fA=sigf(acc[2]), gA=tanhfast(acc[4]), oA=sigf(acc[6]);
        float iB=sigf(acc[1]), fB=sigf(acc[3]), gB=tanhfast(acc[5]), oB=sigf(acc[7]);
        c0 = fA*c0 + iA*gA; float hA = oA*tanhfast(c0);
        c1 = fB*c1 + iB*gB; float hB = oB*tanhfast(c1);
        __syncthreads();
        h_sm[wq][l]=hA; h_sm[wq][l+64]=hB;
        if (s == len_sm[wq]-1){ f0=hA; f1=hB; }
        __syncthreads();
    }
    feat[(w0+wq)*CHID + l]      = __float2bfloat16(f0);
    feat[(w0+wq)*CHID + 64 + l] = __float2bfloat16(f1);
}

// ---------------------------------------------------------------------------
// XW GEMM (per chunk): XWc[tl][2048] = [wemb[x[t]] | feat[t]] @ wWih^T + wb
// ---------------------------------------------------------------------------
__launch_bounds__(256)
__global__ void xw_chunk_kernel(int t0, const int* __restrict__ flagp, const int* __restrict__ x,
                                const void* wemb, const bf16* __restrict__ feat,
                                const void* wWih, const float* __restrict__ wb,
                                bf16* __restrict__ XWc)
{
    int isbf = *flagp;
    __shared__ float    fsm[16][WDIM+CHID];   // 24 KB
    __shared__ uint32_t wsm[256*33];          // 33 KB
    __shared__ int      x_sm[16];
    int tid = threadIdx.x;
    int tblk = blockIdx.x>>3, cblk = blockIdx.x&7;
    int tl0 = tblk*16, c0 = cblk*256;
    int tg0 = t0 + tl0;
    if (tid<16) x_sm[tid] = x[tg0+tid];
    __syncthreads();
    for (int j=tid; j<16*128; j+=256){        // word-embed part (gather raw rows)
        int t=j>>7, kp=j&127;
        uint32_t wv = getpair(wemb, (i64)x_sm[t]*128 + kp, isbf);
        fsm[t][2*kp]=bflo(wv); fsm[t][2*kp+1]=bfhi(wv);
    }
    for (int j=tid; j<16*64; j+=256){         // char-feat part (canonical bf16)
        int t=j>>6, kp=j&63;
        uint32_t fv = ((const uint32_t*)feat)[(i64)(tg0+t)*64 + kp];
        fsm[t][WDIM+2*kp]=bflo(fv); fsm[t][WDIM+2*kp+1]=bfhi(fv);
    }
    float acc[16];
    #pragma unroll
    for (int t=0;t<16;t++) acc[t]=0.f;
    for (int kc=0; kc<6; kc++){
        __syncthreads();
        for (int j=tid; j<8192; j+=256){
            int cc=j>>5, kp=j&31;
            wsm[cc*33+kp] = getpair(wWih, (i64)(c0+cc)*192 + kc*32 + kp, isbf);
        }
        __syncthreads();
        for (int kp=0;kp<32;kp++){
            uint32_t wv = wsm[tid*33+kp];
            float wl=bflo(wv), wh=bfhi(wv);
            #pragma unroll
            for (int t=0;t<16;t++){
                float2 f2 = *(const float2*)&fsm[t][kc*64+2*kp];
                acc[t] += f2.x*wl + f2.y*wh;
            }
        }
    }
    int cg = c0 + tid;
    float bias = wb[cg];
    for (int t=0;t<16;t++)
        XWc[(i64)(tl0+t)*2048 + cg] = __float2bfloat16(acc[t] + bias);
}

// ---------------------------------------------------------------------------
// Word LSTM chunk: persistent, 32 blocks x 256 thr. Block b owns units
// [16b,16b+16) (64 gate rows). Weights f32 in registers (direct from source,
// no bf16 quantization). h via 4-row ring (agent-scope atomics). Per-chunk
// classifier epilogue. OUTPUT: fp32.
// ---------------------------------------------------------------------------
__launch_bounds__(256,1)
__global__ void word_chunk_kernel(int t0, int chLen, const int* __restrict__ flagp,
                                  const void* wWhh, const bf16* __restrict__ XWc,
                                  uint32_t* __restrict__ hring, uint32_t* __restrict__ hs_chunk,
                                  float* __restrict__ cstate, int* __restrict__ cnt,
                                  const void* clsW, const float* __restrict__ clsb_f,
                                  float* __restrict__ out)
{
    int isbf = *flagp;
    __shared__ float h_sm[WHID];
    __shared__ float part[256];
    __shared__ float gv[64];
    int tid=threadIdx.x, b=blockIdx.x;
    int r = tid&63, kq = tid>>6;
    int gate = r>>4, u = r&15;
    int grow = gate*512 + b*16 + u;
    float wreg[128];
    #pragma unroll
    for (int jp=0;jp<64;jp++){
        wreg[2*jp]   = getf(wWhh, (i64)grow*512 + kq*128 + 2*jp,     isbf);
        wreg[2*jp+1] = getf(wWhh, (i64)grow*512 + kq*128 + 2*jp + 1, isbf);
    }
    float c = 0.f;
    if (t0>0 && tid<16) c = cstate[b*16+tid];
    for (int tl=0; tl<chLen; tl++){
        int t = t0 + tl;
        if (t>0){
            if (tid==0){
                while (__hip_atomic_load(&cnt[t-1], __ATOMIC_ACQUIRE, __HIP_MEMORY_SCOPE_AGENT) < GWORD)
                    __builtin_amdgcn_s_sleep(1);
            }
            __syncthreads();
        }
        float xwv = (tid<64) ? bf2f(((const uint16_t*)XWc)[(i64)tl*2048 + grow]) : 0.f;
        uint32_t hv2 = __hip_atomic_load(hring + (t&3)*256 + tid,
                                         __ATOMIC_RELAXED, __HIP_MEMORY_SCOPE_AGENT);
        h_sm[2*tid]   = bflo(hv2);
        h_sm[2*tid+1] = bfhi(hv2);
        __syncthreads();
        float acc=0.f;
        const float* hq = h_sm + kq*128;
        #pragma unroll
        for (int jp=0;jp<64;jp++){
            float2 h2 = *(const float2*)&hq[2*jp];
            acc += h2.x*wreg[2*jp] + h2.y*wreg[2*jp+1];
        }
        part[tid]=acc;
        __syncthreads();
        if (tid<64) gv[tid] = part[tid]+part[tid+64]+part[tid+128]+part[tid+192] + xwv;
        __syncthreads();
        if (tid<16){
            float iv=sigf(gv[tid]), fv=sigf(gv[16+tid]), gg=tanhfast(gv[32+tid]), ov=sigf(gv[48+tid]);
            c = fv*c + iv*gg;
            float hv = ov*tanhfast(c);
            gv[tid] = hv;
        }
        __syncthreads();
        if (tid<8){
            uint32_t lo = f2bb(gv[2*tid]), hi = f2bb(gv[2*tid+1]);
            uint32_t v = lo | (hi<<16);
            __hip_atomic_store(hring + ((t+1)&3)*256 + b*8 + tid, v,
                               __ATOMIC_RELAXED, __HIP_MEMORY_SCOPE_AGENT);
            __hip_atomic_store(hs_chunk + (i64)tl*256 + b*8 + tid, v,
                               __ATOMIC_RELAXED, __HIP_MEMORY_SCOPE_AGENT);
        }
        if (tid==0) __hip_atomic_fetch_add(&cnt[t], 1, __ATOMIC_RELEASE, __HIP_MEMORY_SCOPE_AGENT);
    }
    if (tid<16) cstate[b*16+tid] = c;
    if (tid==0){
        while (__hip_atomic_load(&cnt[t0+chLen-1], __ATOMIC_ACQUIRE, __HIP_MEMORY_SCOPE_AGENT) < GWORD)
            __builtin_amdgcn_s_sleep(1);
    }
    __syncthreads();
    // classifier: block b owns local timesteps [b*tlPer, (b+1)*tlPer)  (fp32 out)
    int tlPer = chLen >> 5;
    int pairs = tlPer*64;
    for (int p0=0; p0<pairs; p0+=256){
        int p = p0 + tid;
        if (p < pairs){
            int tl = b*tlPer + (p>>6), tag = p&63;
            const uint32_t* hrow = hs_chunk + (i64)tl*256;
            float acc = clsb_f[tag];
            for (int kp=0;kp<256;kp++){
                uint32_t hw=hrow[kp], cw=getpair(clsW,(i64)tag*256+kp,isbf);
                acc += bflo(hw)*bflo(cw) + bfhi(hw)*bfhi(cw);
            }
            out[(i64)(t0+tl)*64 + tag] = acc;
        }
    }
}

extern "C" void kernel_launch(void* const* d_in, const int* in_sizes, int n_in,
                              void* d_out, int out_size, void* d_ws, size_t ws_size,
                              hipStream_t stream) {
    const int* x     = (const int*)d_in[0];
    const int* chars = (const int*)d_in[1];
    const int* lens  = (const int*)d_in[2];
    const void* wemb = d_in[3];
    const void* cemb = d_in[4];
    const void* cWih = d_in[5];
    const void* cWhh = d_in[6];
    const void* cbih = d_in[7];
    const void* cbhh = d_in[8];
    const void* wWih = d_in[9];
    const void* wWhh = d_in[10];
    const void* wbih = d_in[11];
    const void* wbhh = d_in[12];
    const void* clsW = d_in[13];
    const void* clsb = d_in[14];

    char* ws = (char*)d_ws;
    size_t off = 0;
    int*      flag    = (int*)(ws+off);      off += 256;
    float*    E       = (float*)(ws+off);    off += 128*512*4;            // 256 KB
    uint32_t* whhT_c  = (uint32_t*)(ws+off); off += 64*512*4;             // 128 KB
    float*    wb      = (float*)(ws+off);    off += 2048*4;               // 8 KB
    float*    clsb_f  = (float*)(ws+off);    off += 256;
    uint32_t* hring   = (uint32_t*)(ws+off); off += 4*256*4;              // 4 KB
    float*    cstate  = (float*)(ws+off);    off += 512*4;                // 2 KB
    int*      cnt     = (int*)(ws+off);      off += (size_t)S_LEN*4;      // 32 KB
    bf16*     feat    = (bf16*)(ws+off);     off += (size_t)S_LEN*CHID*2; // 2 MB
    size_t fixed = off;                                                   // ~2.47 MB

    // adaptive chunk size: XWc (CH*2048*2B) + hs_chunk (CH*256*4B) = CH*5120B
    int CH = 64;
    for (int cc=1024; cc>=64; cc>>=1){
        if (fixed + (size_t)cc*5120 <= ws_size){ CH = cc; break; }
    }
    bf16*     XWc      = (bf16*)(ws+off);     off += (size_t)CH*2048*2;
    uint32_t* hs_chunk = (uint32_t*)(ws+off); off += (size_t)CH*256*4;

    sniff_kernel<<<1,64,0,stream>>>((const uint32_t*)wWhh, flag);
    canon_kernel<<<133,256,0,stream>>>(flag, cemb, cWih, cWhh, cbih, cbhh,
                                       wbih, wbhh, clsb,
                                       E, whhT_c, wb, clsb_f, cnt, hring);
    char_lstm_kernel<<<S_LEN/8,512,0,stream>>>(chars, lens, E, whhT_c, feat);
    int nchunk = S_LEN / CH;
    for (int k=0; k<nchunk; k++){
        xw_chunk_kernel<<<(CH/16)*8,256,0,stream>>>(k*CH, flag, x, wemb, feat, wWih, wb, XWc);
        word_chunk_kernel<<<GWORD,256,0,stream>>>(k*CH, CH, flag, wWhh, XWc, hring, hs_chunk,
                                                  cstate, cnt, clsW, clsb_f, (float*)d_out);
    }
}

// Round 6
// 19192.729 us; speedup vs baseline: 1.7483x; 1.7483x over previous
//
#include <hip/hip_runtime.h>
#include <hip/hip_bf16.h>
#include <stdint.h>

#define S_LEN 8192
#define CH_L 16
#define CDIM 64
#define WDIM 256
#define CHID 128
#define WHID 512
#define NTAG 64
#define GWORD 32

typedef __hip_bfloat16 bf16;
typedef long long i64;

__device__ __forceinline__ float bflo(uint32_t w){ union{uint32_t u;float f;}v; v.u=w<<16; return v.f; }
__device__ __forceinline__ float bfhi(uint32_t w){ union{uint32_t u;float f;}v; v.u=w&0xffff0000u; return v.f; }
__device__ __forceinline__ float bf2f(uint16_t h){ union{uint32_t u;float f;}v; v.u=((uint32_t)h)<<16; return v.f; }
__device__ __forceinline__ uint16_t f2bb(float f){ bf16 h=__float2bfloat16(f); union{uint16_t u;bf16 b;}v; v.b=h; return v.u; }
__device__ __forceinline__ float sigf(float x){ return 1.0f/(1.0f+__expf(-x)); }
__device__ __forceinline__ float tanhfast(float x){ x=fminf(fmaxf(x,-15.f),15.f); float e=__expf(2.f*x); return (e-1.f)/(e+1.f); }

__device__ __forceinline__ float getf(const void* p, i64 i, int isbf){
    return isbf ? bf2f(((const uint16_t*)p)[i]) : ((const float*)p)[i];
}
__device__ __forceinline__ uint32_t getpair(const void* p, i64 j, int isbf){
    if (isbf) return ((const uint32_t*)p)[j];
    float a=((const float*)p)[2*j], b=((const float*)p)[2*j+1];
    return (uint32_t)f2bb(a) | ((uint32_t)f2bb(b)<<16);
}

// ---------------------------------------------------------------------------
// Sniff: bf16 vs fp32 for the float inputs (expected fp32 -> flag=0).
// ---------------------------------------------------------------------------
__global__ void sniff_kernel(const uint32_t* __restrict__ wWhh_raw, int* __restrict__ flag){
    int lane = threadIdx.x;
    uint32_t w = wWhh_raw[lane];
    uint16_t h = (uint16_t)(w & 0xFFFFu);
    uint32_t e = (h>>7)&0xFF;
    int ok = (h==0) || (e>=0x58 && e<=0x7E);
    unsigned long long m = __ballot(ok);
    if (lane==0) *flag = (__popcll(m) >= 32) ? 1 : 0;
}

// ---------------------------------------------------------------------------
// Canonicalize: E table, cWhh transpose, summed biases, cnt, h slot 0.
// ---------------------------------------------------------------------------
__global__ void canon_kernel(const int* __restrict__ flag,
    const void* cemb, const void* cWih, const void* cWhh,
    const void* cbih, const void* cbhh, const void* wbih, const void* wbhh,
    const void* clsb,
    float* __restrict__ E, uint32_t* __restrict__ whhT_c, float* __restrict__ wb,
    float* __restrict__ clsb_f, int* __restrict__ cnt, uint32_t* __restrict__ hsl)
{
    int isbf = *flag;
    int blk = blockIdx.x, tid = threadIdx.x;
    if (blk < 128) {                       // E[ch][512] = cemb[ch] @ cWih^T + biases
        int ch = blk;
        for (int rr=0; rr<2; rr++){
            int r = tid + rr*256;
            float acc = getf(cbih,r,isbf) + getf(cbhh,r,isbf);
            for (int k=0;k<64;k++)
                acc += getf(cemb,(i64)ch*64+k,isbf)*getf(cWih,(i64)r*64+k,isbf);
            E[ch*512+r] = acc;
        }
    } else if (blk < 132) {                // cWhh [512][128] -> [kp 64][row 512] pairs
        int base = (blk-128)*8192;
        for (int i=0;i<32;i++){
            int j = base + tid + i*256;
            int kp=j>>9, row=j&511;
            whhT_c[j] = getpair(cWhh,(i64)row*64+kp,isbf);
        }
    } else {                               // wb, clsb_f, cnt, h slot 0 (tag 0, value 0)
        for (int j=tid;j<2048;j+=256) wb[j] = getf(wbih,j,isbf)+getf(wbhh,j,isbf);
        for (int j=tid;j<64;j+=256)   clsb_f[j] = getf(clsb,j,isbf);
        for (int j=tid;j<256;j+=256)  cnt[j]=0;
        for (int j=tid;j<512;j+=256)  hsl[j]=0u;
    }
}

// ---------------------------------------------------------------------------
// Char LSTM: 8 words/block, 512 threads.
// ---------------------------------------------------------------------------
__launch_bounds__(512)
__global__ void char_lstm_kernel(const int* __restrict__ chars, const int* __restrict__ lens,
                                 const float* __restrict__ E, const uint32_t* __restrict__ whhT,
                                 bf16* __restrict__ feat)
{
    __shared__ float h_sm[8][CHID];
    __shared__ int   ch_sm[8][CH_L];
    __shared__ int   len_sm[8];
    int tid = threadIdx.x;
    int w0  = blockIdx.x*8;
    if (tid < 128){ int w=tid>>4, s=tid&15; ch_sm[w][s] = chars[(w0+w)*CH_L + s]; }
    if (tid < 8)  len_sm[tid] = lens[w0+tid];
    int wq = tid>>6, l = tid&63;
    h_sm[wq][l]=0.f; h_sm[wq][l+64]=0.f;
    float c0=0.f, c1=0.f, f0=0.f, f1=0.f;
    __syncthreads();
    for (int s=0; s<CH_L; s++){
        int ch = ch_sm[wq][s];
        const float* Erow = E + ch*512;
        float acc[8];
        #pragma unroll
        for (int r=0;r<8;r++) acc[r]=Erow[r*64+l];
        for (int kp=0; kp<64; kp++){
            float2 h2 = *(const float2*)&h_sm[wq][2*kp];
            const uint32_t* wp = whhT + kp*512 + l;
            #pragma unroll
            for (int r=0;r<8;r++){
                uint32_t wv = wp[r*64];
                acc[r] += h2.x*bflo(wv) + h2.y*bfhi(wv);
            }
        }
        float iA=sigf(acc[0]), fA=sigf(acc[2]), gA=tanhfast(acc[4]), oA=sigf(acc[6]);
        float iB=sigf(acc[1]), fB=sigf(acc[3]), gB=tanhfast(acc[5]), oB=sigf(acc[7]);
        c0 = fA*c0 + iA*gA; float hA = oA*tanhfast(c0);
        c1 = fB*c1 + iB*gB; float hB = oB*tanhfast(c1);
        __syncthreads();
        h_sm[wq][l]=hA; h_sm[wq][l+64]=hB;
        if (s == len_sm[wq]-1){ f0=hA; f1=hB; }
        __syncthreads();
    }
    feat[(w0+wq)*CHID + l]      = __float2bfloat16(f0);
    feat[(w0+wq)*CHID + 64 + l] = __float2bfloat16(f1);
}

// ---------------------------------------------------------------------------
// XW GEMM (per chunk): XWc[tl][2048] = [wemb[x[t]] | feat[t]] @ wWih^T + wb
// ---------------------------------------------------------------------------
__launch_bounds__(256)
__global__ void xw_chunk_kernel(int t0, const int* __restrict__ flagp, const int* __restrict__ x,
                                const void* wemb, const bf16* __restrict__ feat,
                                const void* wWih, const float* __restrict__ wb,
                                bf16* __restrict__ XWc)
{
    int isbf = *flagp;
    __shared__ float    fsm[16][WDIM+CHID];
    __shared__ uint32_t wsm[256*33];
    __shared__ int      x_sm[16];
    int tid = threadIdx.x;
    int tblk = blockIdx.x>>3, cblk = blockIdx.x&7;
    int tl0 = tblk*16, c0 = cblk*256;
    int tg0 = t0 + tl0;
    if (tid<16) x_sm[tid] = x[tg0+tid];
    __syncthreads();
    for (int j=tid; j<16*128; j+=256){
        int t=j>>7, kp=j&127;
        uint32_t wv = getpair(wemb, (i64)x_sm[t]*128 + kp, isbf);
        fsm[t][2*kp]=bflo(wv); fsm[t][2*kp+1]=bfhi(wv);
    }
    for (int j=tid; j<16*64; j+=256){
        int t=j>>6, kp=j&63;
        uint32_t fv = ((const uint32_t*)feat)[(i64)(tg0+t)*64 + kp];
        fsm[t][WDIM+2*kp]=bflo(fv); fsm[t][WDIM+2*kp+1]=bfhi(fv);
    }
    float acc[16];
    #pragma unroll
    for (int t=0;t<16;t++) acc[t]=0.f;
    for (int kc=0; kc<6; kc++){
        __syncthreads();
        for (int j=tid; j<8192; j+=256){
            int cc=j>>5, kp=j&31;
            wsm[cc*33+kp] = getpair(wWih, (i64)(c0+cc)*192 + kc*32 + kp, isbf);
        }
        __syncthreads();
        for (int kp=0;kp<32;kp++){
            uint32_t wv = wsm[tid*33+kp];
            float wl=bflo(wv), wh=bfhi(wv);
            #pragma unroll
            for (int t=0;t<16;t++){
                float2 f2 = *(const float2*)&fsm[t][kc*64+2*kp];
                acc[t] += f2.x*wl + f2.y*wh;
            }
        }
    }
    int cg = c0 + tid;
    float bias = wb[cg];
    for (int t=0;t<16;t++)
        XWc[(i64)(tl0+t)*2048 + cg] = __float2bfloat16(acc[t] + bias);
}

// ---------------------------------------------------------------------------
// Word LSTM chunk: persistent, 32 blocks x 256 thr. Block b owns units
// [16b,16b+16) (64 gate rows). Weights in float4 w4[32] REGISTERS (unrolled
// const indices). h exchange: fp32 h words with 2 low mantissa bits stolen as
// a step tag (slot=t&3, tag=(t>>2)&3) — the poll IS the data load, one
// relaxed agent-scope u64 load per thread. Max skew between blocks is 1 step
// (step t needs all h of t-1), so 4-slot/2-bit tags can't alias. 0xAA poison
// has tag 2, never matching the first use of a slot (tags 0).
// ---------------------------------------------------------------------------
__launch_bounds__(256,1)
__global__ void word_chunk_kernel(int t0, int chLen, int cidx, const int* __restrict__ flagp,
                                  const void* wWhh, const bf16* __restrict__ XWc,
                                  uint32_t* __restrict__ hsl, uint32_t* __restrict__ hs_chunk,
                                  float* __restrict__ cstate, int* __restrict__ cnt,
                                  const void* clsW, const float* __restrict__ clsb_f,
                                  float* __restrict__ out)
{
    int isbf = *flagp;
    __shared__ float h_sm[WHID];
    __shared__ float part[256];
    __shared__ float gv[64];
    int tid=threadIdx.x, b=blockIdx.x;
    int r = tid&63, kq = tid>>6;
    int gate = r>>4, u = r&15;
    int grow = gate*512 + b*16 + u;           // global gate row
    float4 w4[32];                            // 128 f32 weights, k = kq*128 + 4j..
    if (isbf){
        const uint2* src = (const uint2*)wWhh;
        #pragma unroll
        for (int j=0;j<32;j++){
            uint2 rr = src[(i64)grow*128 + kq*32 + j];
            w4[j] = make_float4(bflo(rr.x), bfhi(rr.x), bflo(rr.y), bfhi(rr.y));
        }
    } else {
        const float4* src = (const float4*)wWhh;
        #pragma unroll
        for (int j=0;j<32;j++) w4[j] = src[(i64)grow*128 + kq*32 + j];
    }
    float c = 0.f;
    if (t0>0 && tid<16) c = cstate[b*16+tid];
    for (int tl=0; tl<chLen; tl++){
        int t = t0 + tl;
        // prefetch xw (independent of h) so it rides under the poll
        float xwv = (tid<64) ? bf2f(((const uint16_t*)XWc)[(i64)tl*2048 + grow]) : 0.f;
        // poll own u64 of h slot (2 fp32 words, each self-tagged)
        uint32_t tag = (uint32_t)((t>>2)&3);
        const unsigned long long* hp =
            (const unsigned long long*)(hsl + (size_t)(t&3)*512) + tid;
        unsigned long long uv;
        for(;;){
            uv = __hip_atomic_load(hp, __ATOMIC_RELAXED, __HIP_MEMORY_SCOPE_AGENT);
            if ((((uint32_t)uv)&3u)==tag && (((uint32_t)(uv>>32))&3u)==tag) break;
        }
        h_sm[2*tid]   = __uint_as_float((uint32_t)uv);
        h_sm[2*tid+1] = __uint_as_float((uint32_t)(uv>>32));
        __syncthreads();
        float a0=0.f,a1=0.f,a2=0.f,a3=0.f;
        const float* hq = h_sm + kq*128;
        #pragma unroll
        for (int j=0;j<32;j++){
            float4 h4 = *(const float4*)&hq[4*j];
            a0 += h4.x*w4[j].x; a1 += h4.y*w4[j].y;
            a2 += h4.z*w4[j].z; a3 += h4.w*w4[j].w;
        }
        part[tid] = (a0+a1)+(a2+a3);
        __syncthreads();
        // epilogue: wave0-internal (lanes 0-63), LDS ops ordered within a wave
        if (tid<64) gv[tid] = part[tid]+part[tid+64]+part[tid+128]+part[tid+192] + xwv;
        __builtin_amdgcn_wave_barrier();
        if (tid<16){
            float iv=sigf(gv[tid]), fv=sigf(gv[16+tid]), gg=tanhfast(gv[32+tid]), ov=sigf(gv[48+tid]);
            c = fv*c + iv*gg;
            float hv = ov*tanhfast(c);
            uint32_t hb = (__float_as_uint(hv) & ~3u) | (uint32_t)(((t+1)>>2)&3);
            __hip_atomic_store(hsl + (size_t)((t+1)&3)*512 + b*16 + tid, hb,
                               __ATOMIC_RELAXED, __HIP_MEMORY_SCOPE_AGENT);
            gv[tid] = hv;
        }
        __builtin_amdgcn_wave_barrier();
        if (tid<8){
            uint32_t lo = f2bb(gv[2*tid]), hi = f2bb(gv[2*tid+1]);
            __hip_atomic_store(hs_chunk + (i64)tl*256 + b*8 + tid, lo | (hi<<16),
                               __ATOMIC_RELAXED, __HIP_MEMORY_SCOPE_AGENT);
        }
    }
    if (tid<16) cstate[b*16+tid] = c;
    // end-of-chunk all-arrive barrier (release covers wave0's global stores;
    // all hs_chunk stores were made by wave0)
    if (tid==0){
        __hip_atomic_fetch_add(&cnt[cidx], 1, __ATOMIC_RELEASE, __HIP_MEMORY_SCOPE_AGENT);
        while (__hip_atomic_load(&cnt[cidx], __ATOMIC_ACQUIRE, __HIP_MEMORY_SCOPE_AGENT) < GWORD)
            __builtin_amdgcn_s_sleep(1);
    }
    __syncthreads();
    // classifier: block b owns local timesteps [b*tlPer, (b+1)*tlPer)
    int tlPer = chLen >> 5;
    int pairs = tlPer*64;
    for (int p0=0; p0<pairs; p0+=256){
        int p = p0 + tid;
        if (p < pairs){
            int tl = b*tlPer + (p>>6), tag2 = p&63;
            const uint32_t* hrow = hs_chunk + (i64)tl*256;
            float acc = clsb_f[tag2];
            for (int kp=0;kp<256;kp++){
                uint32_t hw=hrow[kp], cw=getpair(clsW,(i64)tag2*256+kp,isbf);
                acc += bflo(hw)*bflo(cw) + bfhi(hw)*bfhi(cw);
            }
            out[(i64)(t0+tl)*64 + tag2] = acc;
        }
    }
}

extern "C" void kernel_launch(void* const* d_in, const int* in_sizes, int n_in,
                              void* d_out, int out_size, void* d_ws, size_t ws_size,
                              hipStream_t stream) {
    const int* x     = (const int*)d_in[0];
    const int* chars = (const int*)d_in[1];
    const int* lens  = (const int*)d_in[2];
    const void* wemb = d_in[3];
    const void* cemb = d_in[4];
    const void* cWih = d_in[5];
    const void* cWhh = d_in[6];
    const void* cbih = d_in[7];
    const void* cbhh = d_in[8];
    const void* wWih = d_in[9];
    const void* wWhh = d_in[10];
    const void* wbih = d_in[11];
    const void* wbhh = d_in[12];
    const void* clsW = d_in[13];
    const void* clsb = d_in[14];

    char* ws = (char*)d_ws;
    size_t off = 0;
    int*      flag    = (int*)(ws+off);      off += 256;
    float*    E       = (float*)(ws+off);    off += 128*512*4;            // 256 KB
    uint32_t* whhT_c  = (uint32_t*)(ws+off); off += 64*512*4;             // 128 KB
    float*    wb      = (float*)(ws+off);    off += 2048*4;               // 8 KB
    float*    clsb_f  = (float*)(ws+off);    off += 256;
    uint32_t* hsl     = (uint32_t*)(ws+off); off += 4*512*4;              // 8 KB
    float*    cstate  = (float*)(ws+off);    off += 512*4;                // 2 KB
    int*      cnt     = (int*)(ws+off);      off += 256*4;                // 1 KB
    bf16*     feat    = (bf16*)(ws+off);     off += (size_t)S_LEN*CHID*2; // 2 MB
    size_t fixed = off;                                                   // ~2.44 MB

    // adaptive chunk: XWc (CH*2048*2B) + hs_chunk (CH*256*4B) = CH*5120B
    int CH = 64;
    for (int cc=1024; cc>=64; cc>>=1){
        if (fixed + (size_t)cc*5120 <= ws_size){ CH = cc; break; }
    }
    bf16*     XWc      = (bf16*)(ws+off);     off += (size_t)CH*2048*2;
    uint32_t* hs_chunk = (uint32_t*)(ws+off); off += (size_t)CH*256*4;

    sniff_kernel<<<1,64,0,stream>>>((const uint32_t*)wWhh, flag);
    canon_kernel<<<133,256,0,stream>>>(flag, cemb, cWih, cWhh, cbih, cbhh,
                                       wbih, wbhh, clsb,
                                       E, whhT_c, wb, clsb_f, cnt, hsl);
    char_lstm_kernel<<<S_LEN/8,512,0,stream>>>(chars, lens, E, whhT_c, feat);
    int nchunk = S_LEN / CH;
    for (int k=0; k<nchunk; k++){
        xw_chunk_kernel<<<(CH/16)*8,256,0,stream>>>(k*CH, flag, x, wemb, feat, wWih, wb, XWc);
        word_chunk_kernel<<<GWORD,256,0,stream>>>(k*CH, CH, k, flag, wWhh, XWc, hsl, hs_chunk,
                                                  cstate, cnt, clsW, clsb_f, (float*)d_out);
    }
}